// Round 4
// baseline (335.354 us; speedup 1.0000x reference)
//
#include <hip/hip_runtime.h>
#include <math.h>

#define NHEADS 8
#define DIMC   512
#define SEQC   128
#define LAGC   5
#define DHC    64
#define BATCHC 64

typedef __attribute__((ext_vector_type(8))) short short8;
typedef __attribute__((ext_vector_type(4))) float f32x4;
typedef __attribute__((ext_vector_type(8))) unsigned short ushort8;

// fp32 -> bf16 round-to-nearest-even
__device__ inline unsigned short f2b(float f) {
    unsigned int x = __float_as_uint(f);
    x += 0x7fffu + ((x >> 16) & 1u);
    return (unsigned short)(x >> 16);
}
__device__ inline float b2f(unsigned short u) {
    return __uint_as_float((unsigned)u << 16);
}

// async global->LDS, 16B/lane, LDS dest = wave-uniform base + lane*16
__device__ inline void load_lds16(const void* g, void* l) {
    __builtin_amdgcn_global_load_lds(
        (const __attribute__((address_space(1))) void*)g,
        (__attribute__((address_space(3))) void*)l, 16, 0, 0);
}

// ---------------------------------------------------------------------------
// elementwise fp32 -> bf16, 8 elems/thread/iter
// ---------------------------------------------------------------------------
__global__ __launch_bounds__(256)
void f32_to_bf16_kernel(const float* __restrict__ in, unsigned short* __restrict__ out,
                        long long n8)
{
    for (long long i = (long long)blockIdx.x * blockDim.x + threadIdx.x; i < n8;
         i += (long long)gridDim.x * blockDim.x) {
        const float4 a = *(const float4*)(in + i * 8);
        const float4 b = *(const float4*)(in + i * 8 + 4);
        uint4 u;
        u.x = (unsigned)f2b(a.x) | ((unsigned)f2b(a.y) << 16);
        u.y = (unsigned)f2b(a.z) | ((unsigned)f2b(a.w) << 16);
        u.z = (unsigned)f2b(b.x) | ((unsigned)f2b(b.y) << 16);
        u.w = (unsigned)f2b(b.z) | ((unsigned)f2b(b.w) << 16);
        *(uint4*)(out + i * 8) = u;
    }
}

// ---------------------------------------------------------------------------
// W[K][N] fp32 -> Wt[N][K] bf16  (32x32 tile, +1 pad)
// ---------------------------------------------------------------------------
__global__ __launch_bounds__(256)
void transpose_bf16_kernel(const float* __restrict__ W, unsigned short* __restrict__ Wt,
                           int K, int N)
{
    __shared__ float t[32][33];
    const int k0 = blockIdx.x * 32, n0 = blockIdx.y * 32;
    const int tx = threadIdx.x & 31, ty = threadIdx.x >> 5;   // 32 x 8
    #pragma unroll
    for (int i = 0; i < 32; i += 8)
        t[ty + i][tx] = W[(long long)(k0 + ty + i) * N + n0 + tx];
    __syncthreads();
    #pragma unroll
    for (int i = 0; i < 32; i += 8)
        Wt[(long long)(n0 + ty + i) * K + k0 + tx] = f2b(t[tx][ty + i]);
}

// ---------------------------------------------------------------------------
// bf16 MFMA GEMM (m97 2-barrier structure): C[M,N] = A @ Bt^T + bias
//   A  : bf16, row m at A + (m/group)*gstride + (m%group)*lda  (k-contig)
//   Bt : bf16 [N][K] row-major (k-contig)
//   bias: cols < nsplit from bias1, cols >= nsplit from bias2
// 128x128 tile, BK=32, 4 waves, wave -> 64x64 out (4x4 grid of 16x16x32 MFMA)
// ---------------------------------------------------------------------------
template<bool BF16OUT>
__global__ __launch_bounds__(256)
void gemm_mfma(const unsigned short* __restrict__ A, const unsigned short* __restrict__ Bt,
               const float* __restrict__ bias1, const float* __restrict__ bias2, int nsplit,
               void* __restrict__ Cv, int N, int K, int lda, int group, long long gstride)
{
    __shared__ __align__(16) unsigned short As[128][32];   // 8 KB
    __shared__ __align__(16) unsigned short Bs[128][32];   // 8 KB

    const int tid  = threadIdx.x;
    const int w    = tid >> 6;
    const int lane = tid & 63;
    const int bm = blockIdx.y * 128;
    const int bn = blockIdx.x * 128;
    const int wr = (w >> 1) * 64;
    const int wc = (w & 1) * 64;

    // staging: wave w fills LDS rows [32w, 32w+32): lane -> row 32w+(lane>>2),
    // 16B chunk (lane&3)  (matches global_load_lds's base+lane*16 linear write)
    const int srow   = w * 32 + (lane >> 2);
    const int schunk = (lane & 3) * 8;
    const int am0 = bm + srow;
    const int am1 = am0 + 16;
    const unsigned short* ag0 = A + (long long)(am0 / group) * gstride
                                  + (long long)(am0 % group) * lda + schunk;
    const unsigned short* ag1 = A + (long long)(am1 / group) * gstride
                                  + (long long)(am1 % group) * lda + schunk;
    const unsigned short* bg0 = Bt + (long long)(bn + srow) * K + schunk;
    const unsigned short* bg1 = bg0 + (long long)16 * K;
    unsigned short* lA0 = &As[w * 32][0];
    unsigned short* lA1 = &As[w * 32 + 16][0];
    unsigned short* lB0 = &Bs[w * 32][0];
    unsigned short* lB1 = &Bs[w * 32 + 16][0];

    const int n  = lane & 15;
    const int g8 = (lane >> 4) * 8;

    f32x4 acc[4][4];
    #pragma unroll
    for (int i = 0; i < 4; ++i)
        #pragma unroll
        for (int j = 0; j < 4; ++j) acc[i][j] = (f32x4){0.f, 0.f, 0.f, 0.f};

    for (int k0 = 0; k0 < K; k0 += 32) {
        load_lds16(ag0, lA0);
        load_lds16(ag1, lA1);
        load_lds16(bg0, lB0);
        load_lds16(bg1, lB1);
        ag0 += 32; ag1 += 32; bg0 += 32; bg1 += 32;
        __syncthreads();                       // drains vmcnt -> tiles visible

        short8 af[4], bf[4];
        #pragma unroll
        for (int t = 0; t < 4; ++t) {
            af[t] = *(const short8*)&As[wr + t * 16 + n][g8];
            bf[t] = *(const short8*)&Bs[wc + t * 16 + n][g8];
        }
        #pragma unroll
        for (int i = 0; i < 4; ++i)
            #pragma unroll
            for (int j = 0; j < 4; ++j)
                acc[i][j] = __builtin_amdgcn_mfma_f32_16x16x32_bf16(
                    af[i], bf[j], acc[i][j], 0, 0, 0);
        __syncthreads();                       // reads done before next overwrite
    }

    // epilogue: C/D layout col = lane&15, row = 4*(lane>>4)+reg  [m89]
    const bool second = (bn >= nsplit);
    const float* bp = second ? bias2 : bias1;
    const int boff = second ? nsplit : 0;
    const int crow0 = bm + wr + (lane >> 4) * 4;
    const int ccol0 = bn + wc + n;
    float bvals[4];
    #pragma unroll
    for (int j = 0; j < 4; ++j) bvals[j] = bp[ccol0 + j * 16 - boff];
    #pragma unroll
    for (int i = 0; i < 4; ++i)
        #pragma unroll
        for (int j = 0; j < 4; ++j) {
            const int col = ccol0 + j * 16;
            #pragma unroll
            for (int r = 0; r < 4; ++r) {
                const float v = acc[i][j][r] + bvals[j];
                const long long idx = (long long)(crow0 + i * 16 + r) * N + col;
                if (BF16OUT) ((unsigned short*)Cv)[idx] = f2b(v);
                else         ((float*)Cv)[idx] = v;
            }
        }
}

// ---------------------------------------------------------------------------
// MFMA attention: one block per (b,h), all 5 lags fused (Q, V^T staged once).
// 256 threads = 4 waves; wave w owns S/O rows [32w, 32w+32).
// Per lag: S = Q K_l^T (16x16x32 bf16 MFMA, causal block-skip) -> no-max
// softmax in regs (exp2 fused scale, 16-lane shuffle row-sum) -> P bf16 to
// LDS -> O_l = P V. K LDS region aliases P region (3 barriers/lag).
// K_{l+1} prefetched into regs under softmax/PV.
// Layout notes: P/V^T LDS stride 136 bf16 (272B: 16B-aligned, 2-way banks);
// K stride 72 (144B: 16B-aligned, 2-way banks).
// ---------------------------------------------------------------------------
__global__ __launch_bounds__(256)
void attn_mfma_kernel(const unsigned short* __restrict__ QV,
                      const unsigned short* __restrict__ Kp,
                      unsigned short* __restrict__ inter)
{
    __shared__ __align__(16) unsigned short PK[128 * 136];  // P region / K region (aliased)
    __shared__ __align__(16) unsigned short Vt[64 * 136];   // V transposed [d][j]

    const int bid = blockIdx.x;            // b*8 + h
    const int h = bid & 7;
    const int b = bid >> 3;
    const int tid = threadIdx.x;
    const int w = tid >> 6, lane = tid & 63;
    const int n = lane & 15, g = lane >> 4;
    const int g8 = g * 8;
    const int wr = w * 32;

    // ---- stage V transposed: thread t covers row j=t>>1, d-chunk (t&1)*32 ----
    {
        const int j = tid >> 1, d0 = (tid & 1) * 32;
        const unsigned short* vsrc = QV + ((long long)(b * SEQC + j)) * (2 * DIMC)
                                        + DIMC + h * DHC + d0;
        ushort8 vv[4];
        #pragma unroll
        for (int c = 0; c < 4; ++c) vv[c] = *(const ushort8*)(vsrc + c * 8);
        #pragma unroll
        for (int c = 0; c < 4; ++c)
            #pragma unroll
            for (int e = 0; e < 8; ++e)
                Vt[(d0 + c * 8 + e) * 136 + j] = vv[c][e];
    }

    // ---- Q fragments in regs for whole kernel: rows wr+rb*16+n, k=ks*32+g8 ----
    short8 qf[2][2];
    #pragma unroll
    for (int rb = 0; rb < 2; ++rb)
        #pragma unroll
        for (int ks = 0; ks < 2; ++ks)
            qf[rb][ks] = *(const short8*)(QV + ((long long)(b * SEQC + wr + rb * 16 + n)) * (2 * DIMC)
                                             + h * DHC + ks * 32 + g8);

    // ---- K load mapping: thread t covers row j=t>>1, chunk (t&1)*32 ----
    const int jrow = tid >> 1, jc = (tid & 1) * 32;
    const unsigned short* ksrc = Kp + ((long long)((b * LAGC) * SEQC + jrow)) * DIMC
                                    + h * DHC + jc;
    ushort8 kreg[4];
    #pragma unroll
    for (int c = 0; c < 4; ++c) kreg[c] = *(const ushort8*)(ksrc + c * 8);

    // causal block ranges for this wave (32-col aligned coverage)
    const int cbm0 = (2 * w + 0) | 1;      // S col-blocks for rb=0: cb <= cbm0
    const int cbm1 = (2 * w + 1) | 1;      // rb=1
    const int nk0 = (cbm0 + 1) >> 1;       // PV k-blocks (32 wide) for rb=0
    const int nk1 = (cbm1 + 1) >> 1;

    for (int l = 0; l < LAGC; ++l) {
        __syncthreads();                   // bar1: P/K region free (prev PV reads done)
        #pragma unroll
        for (int c = 0; c < 4; ++c)
            *(ushort8*)&PK[jrow * 72 + jc + c * 8] = kreg[c];   // K region, stride 72
        __syncthreads();                   // bar2: K (and, on l=0, Vt) visible

        // ---- S = Q K^T ----
        f32x4 accs[2][8];
        #pragma unroll
        for (int cb = 0; cb < 8; ++cb) {
            if (cb <= cbm1) {
                const short8 bf0 = *(const short8*)&PK[(cb * 16 + n) * 72 + g8];
                const short8 bf1 = *(const short8*)&PK[(cb * 16 + n) * 72 + 32 + g8];
                if (cb <= cbm0) {
                    accs[0][cb] = (f32x4){0.f, 0.f, 0.f, 0.f};
                    accs[0][cb] = __builtin_amdgcn_mfma_f32_16x16x32_bf16(qf[0][0], bf0, accs[0][cb], 0, 0, 0);
                    accs[0][cb] = __builtin_amdgcn_mfma_f32_16x16x32_bf16(qf[0][1], bf1, accs[0][cb], 0, 0, 0);
                }
                accs[1][cb] = (f32x4){0.f, 0.f, 0.f, 0.f};
                accs[1][cb] = __builtin_amdgcn_mfma_f32_16x16x32_bf16(qf[1][0], bf0, accs[1][cb], 0, 0, 0);
                accs[1][cb] = __builtin_amdgcn_mfma_f32_16x16x32_bf16(qf[1][1], bf1, accs[1][cb], 0, 0, 0);
            }
        }
        __syncthreads();                   // bar3: all waves done reading K region

        // ---- prefetch next lag's K into regs (hides under softmax+PV) ----
        if (l + 1 < LAGC) {
            const unsigned short* knext = ksrc + (long long)(l + 1) * SEQC * DIMC;
            #pragma unroll
            for (int c = 0; c < 4; ++c) kreg[c] = *(const ushort8*)(knext + c * 8);
        }

        // ---- no-max softmax + P(bf16) -> LDS (stride 136) ----
        // s_true = s_raw/8; p = exp2(s_raw * log2e/8); masked (j>row) -> 0
        float inv[2][4];
        #pragma unroll
        for (int rb = 0; rb < 2; ++rb) {
            const int cbm = rb ? cbm1 : cbm0;
            float ps[4] = {0.f, 0.f, 0.f, 0.f};
            #pragma unroll
            for (int cb = 0; cb < 8; ++cb) {
                if (cb <= cbm) {
                    const int j = cb * 16 + n;
                    #pragma unroll
                    for (int r = 0; r < 4; ++r) {
                        const int qr = wr + rb * 16 + 4 * g + r;
                        float p = __builtin_exp2f(accs[rb][cb][r] * 0.18033688f);
                        p = (j <= qr) ? p : 0.f;
                        ps[r] += p;
                        PK[qr * 136 + j] = f2b(p);
                    }
                }
            }
            #pragma unroll
            for (int r = 0; r < 4; ++r) {
                float s = ps[r];
                s += __shfl_xor(s, 1, 64);
                s += __shfl_xor(s, 2, 64);
                s += __shfl_xor(s, 4, 64);
                s += __shfl_xor(s, 8, 64);
                inv[rb][r] = 1.f / s;
            }
        }

        asm volatile("s_waitcnt lgkmcnt(0)" ::: "memory");   // P writes visible wave-wide

        // ---- O = P V ----
        f32x4 acco[2][4];
        #pragma unroll
        for (int rb = 0; rb < 2; ++rb)
            #pragma unroll
            for (int db = 0; db < 4; ++db) acco[rb][db] = (f32x4){0.f, 0.f, 0.f, 0.f};
        #pragma unroll
        for (int ks2 = 0; ks2 < 4; ++ks2) {
            if (ks2 < nk1) {
                short8 bv[4];
                #pragma unroll
                for (int db = 0; db < 4; ++db)
                    bv[db] = *(const short8*)&Vt[(db * 16 + n) * 136 + ks2 * 32 + g8];
                const short8 pa1 = *(const short8*)&PK[(wr + 16 + n) * 136 + ks2 * 32 + g8];
                if (ks2 < nk0) {
                    const short8 pa0 = *(const short8*)&PK[(wr + n) * 136 + ks2 * 32 + g8];
                    #pragma unroll
                    for (int db = 0; db < 4; ++db)
                        acco[0][db] = __builtin_amdgcn_mfma_f32_16x16x32_bf16(pa0, bv[db], acco[0][db], 0, 0, 0);
                }
                #pragma unroll
                for (int db = 0; db < 4; ++db)
                    acco[1][db] = __builtin_amdgcn_mfma_f32_16x16x32_bf16(pa1, bv[db], acco[1][db], 0, 0, 0);
            }
        }

        // ---- O store: inter[(b*S+q)*2560 + l*512 + h*64 + d], bf16 ----
        unsigned short* obase = inter + (long long)(b * SEQC) * (LAGC * DIMC)
                                      + l * DIMC + h * DHC;
        #pragma unroll
        for (int rb = 0; rb < 2; ++rb)
            #pragma unroll
            for (int db = 0; db < 4; ++db)
                #pragma unroll
                for (int r = 0; r < 4; ++r) {
                    const int qr = wr + rb * 16 + 4 * g + r;
                    obase[(long long)qr * (LAGC * DIMC) + db * 16 + n] =
                        f2b(acco[rb][db][r] * inv[rb][r]);
                }
    }
}

// ---------------------------------------------------------------------------
extern "C" void kernel_launch(void* const* d_in, const int* in_sizes, int n_in,
                              void* d_out, int out_size, void* d_ws, size_t ws_size,
                              hipStream_t stream)
{
    const float* input = (const float*)d_in[0];
    const float* Wq = (const float*)d_in[1];
    const float* bq = (const float*)d_in[2];
    const float* Wk = (const float*)d_in[3];
    const float* bk = (const float*)d_in[4];
    const float* Wv = (const float*)d_in[5];
    const float* bv = (const float*)d_in[6];
    const float* Wo = (const float*)d_in[7];
    const float* bo = (const float*)d_in[8];
    float* out = (float*)d_out;

    const long long MQ = (long long)BATCHC * SEQC;          // 8192
    const long long MK = (long long)BATCHC * LAGC * SEQC;   // 40960
    const int BIG = 1 << 30;

    // workspace layout (bf16 everywhere; ~147 MB total)
    unsigned short* in_bf = (unsigned short*)d_ws;          // 40960 x 512
    unsigned short* Wqvt  = in_bf + MK * DIMC;              // 1024 x 512 ([Wq|Wv]^T)
    unsigned short* Wkt   = Wqvt + (long long)2 * DIMC * DIMC;
    unsigned short* Wot   = Wkt + (long long)DIMC * DIMC;   // 512 x 2560
    unsigned short* QV    = Wot + (long long)DIMC * (LAGC * DIMC);  // 8192 x 1024
    unsigned short* Kb    = QV + MQ * (2 * DIMC);           // 40960 x 512
    unsigned short* inter = Kb + MK * DIMC;                 // 8192 x 2560

    // pre-passes
    f32_to_bf16_kernel<<<2048, 256, 0, stream>>>(input, in_bf, MK * DIMC / 8);
    transpose_bf16_kernel<<<dim3(DIMC / 32, DIMC / 32), 256, 0, stream>>>(Wq, Wqvt, DIMC, DIMC);
    transpose_bf16_kernel<<<dim3(DIMC / 32, DIMC / 32), 256, 0, stream>>>(
        Wv, Wqvt + (long long)DIMC * DIMC, DIMC, DIMC);
    transpose_bf16_kernel<<<dim3(DIMC / 32, DIMC / 32), 256, 0, stream>>>(Wk, Wkt, DIMC, DIMC);
    transpose_bf16_kernel<<<dim3(LAGC * DIMC / 32, DIMC / 32), 256, 0, stream>>>(
        Wo, Wot, LAGC * DIMC, DIMC);

    const long long bstride = (long long)LAGC * SEQC * DIMC;
    const unsigned short* last_bf = in_bf + (long long)(LAGC - 1) * SEQC * DIMC;

    // fused Q|V projection: M=8192, N=1024, K=512
    gemm_mfma<true><<<dim3(2 * DIMC / 128, MQ / 128), 256, 0, stream>>>(
        last_bf, Wqvt, bq, bv, DIMC, QV, 2 * DIMC, DIMC, DIMC, SEQC, bstride);
    // K projection over all lags: M=40960, N=512, K=512
    gemm_mfma<true><<<dim3(DIMC / 128, MK / 128), 256, 0, stream>>>(
        in_bf, Wkt, bk, bk, BIG, Kb, DIMC, DIMC, DIMC, BIG, 0);

    // attention: one block per (b,h), 5 lags fused
    attn_mfma_kernel<<<dim3(BATCHC * NHEADS), 256, 0, stream>>>(QV, Kb, inter);

    // out = inter @ Wo + bo: M=8192, N=512, K=2560
    gemm_mfma<false><<<dim3(DIMC / 128, MQ / 128), 256, 0, stream>>>(
        inter, Wot, bo, bo, BIG, out, DIMC, LAGC * DIMC, LAGC * DIMC, BIG, 0);
}

// Round 11
// 315.898 us; speedup vs baseline: 1.0616x; 1.0616x over previous
//
#include <hip/hip_runtime.h>
#include <math.h>

#define NHEADS 8
#define DIMC   512
#define SEQC   128
#define LAGC   5
#define DHC    64
#define BATCHC 64

typedef __attribute__((ext_vector_type(8))) short short8;
typedef __attribute__((ext_vector_type(4))) float f32x4;
typedef __attribute__((ext_vector_type(8))) unsigned short ushort8;

// fp32 -> bf16 round-to-nearest-even
__device__ inline unsigned short f2b(float f) {
    unsigned int x = __float_as_uint(f);
    x += 0x7fffu + ((x >> 16) & 1u);
    return (unsigned short)(x >> 16);
}
__device__ inline float b2f(unsigned short u) {
    return __uint_as_float((unsigned)u << 16);
}

// async global->LDS, 16B/lane, LDS dest = wave-uniform base + lane*16
__device__ inline void load_lds16(const void* g, void* l) {
    __builtin_amdgcn_global_load_lds(
        (const __attribute__((address_space(1))) void*)g,
        (__attribute__((address_space(3))) void*)l, 16, 0, 0);
}

// ---------------------------------------------------------------------------
// elementwise fp32 -> bf16, 8 elems/thread/iter
// ---------------------------------------------------------------------------
__global__ __launch_bounds__(256)
void f32_to_bf16_kernel(const float* __restrict__ in, unsigned short* __restrict__ out,
                        long long n8)
{
    for (long long i = (long long)blockIdx.x * blockDim.x + threadIdx.x; i < n8;
         i += (long long)gridDim.x * blockDim.x) {
        const float4 a = *(const float4*)(in + i * 8);
        const float4 b = *(const float4*)(in + i * 8 + 4);
        uint4 u;
        u.x = (unsigned)f2b(a.x) | ((unsigned)f2b(a.y) << 16);
        u.y = (unsigned)f2b(a.z) | ((unsigned)f2b(a.w) << 16);
        u.z = (unsigned)f2b(b.x) | ((unsigned)f2b(b.y) << 16);
        u.w = (unsigned)f2b(b.z) | ((unsigned)f2b(b.w) << 16);
        *(uint4*)(out + i * 8) = u;
    }
}

// ---------------------------------------------------------------------------
// Batched weight transpose: 4 weights in one launch (z selects which).
// W[K][512] fp32 -> Wt[512][K] bf16.  z=0:Wq z=1:Wv z=2:Wk (K=512), z=3:Wo
// (K=2560). 32x32 LDS tile, +1 pad; out-of-range K-tiles exit uniformly
// before the barrier.
// ---------------------------------------------------------------------------
__global__ __launch_bounds__(256)
void transpose4_bf16_kernel(const float* __restrict__ Wq, const float* __restrict__ Wv,
                            const float* __restrict__ Wk, const float* __restrict__ Wo,
                            unsigned short* __restrict__ Tq, unsigned short* __restrict__ Tv,
                            unsigned short* __restrict__ Tk, unsigned short* __restrict__ To)
{
    const int z = blockIdx.z;
    const int K = (z == 3) ? LAGC * DIMC : DIMC;
    const int k0 = blockIdx.x * 32;
    if (k0 >= K) return;                       // block-uniform: barrier never reached
    const float* W = (z == 0) ? Wq : (z == 1) ? Wv : (z == 2) ? Wk : Wo;
    unsigned short* Wt = (z == 0) ? Tq : (z == 1) ? Tv : (z == 2) ? Tk : To;
    const int N = DIMC;
    const int n0 = blockIdx.y * 32;

    __shared__ float t[32][33];
    const int tx = threadIdx.x & 31, ty = threadIdx.x >> 5;   // 32 x 8
    #pragma unroll
    for (int i = 0; i < 32; i += 8)
        t[ty + i][tx] = W[(long long)(k0 + ty + i) * N + n0 + tx];
    __syncthreads();
    #pragma unroll
    for (int i = 0; i < 32; i += 8)
        Wt[(long long)(n0 + ty + i) * K + k0 + tx] = f2b(t[tx][ty + i]);
}

// ---------------------------------------------------------------------------
// CONTROL ARM: gemm_base — byte-identical structure to the R4 PASSING GEMM
// (single LDS buffer, __syncthreads pair per K-step). Used for QV only.
// C[M,N] = A @ Bt^T + bias; A row m at A + (m/group)*gstride + (m%group)*lda.
// ---------------------------------------------------------------------------
template<bool BF16OUT>
__global__ __launch_bounds__(256)
void gemm_base(const unsigned short* __restrict__ A, const unsigned short* __restrict__ Bt,
               const float* __restrict__ bias1, const float* __restrict__ bias2, int nsplit,
               void* __restrict__ Cv, int N, int K, int lda, int group, long long gstride)
{
    __shared__ __align__(16) unsigned short As[128][32];   // 8 KB
    __shared__ __align__(16) unsigned short Bs[128][32];   // 8 KB

    const int tid  = threadIdx.x;
    const int w    = tid >> 6;
    const int lane = tid & 63;
    const int bm = blockIdx.y * 128;
    const int bn = blockIdx.x * 128;
    const int wr = (w >> 1) * 64;
    const int wc = (w & 1) * 64;

    const int srow   = w * 32 + (lane >> 2);
    const int schunk = (lane & 3) * 8;
    const int am0 = bm + srow;
    const int am1 = am0 + 16;
    const unsigned short* ag0 = A + (long long)(am0 / group) * gstride
                                  + (long long)(am0 % group) * lda + schunk;
    const unsigned short* ag1 = A + (long long)(am1 / group) * gstride
                                  + (long long)(am1 % group) * lda + schunk;
    const unsigned short* bg0 = Bt + (long long)(bn + srow) * K + schunk;
    const unsigned short* bg1 = bg0 + (long long)16 * K;
    unsigned short* lA0 = &As[w * 32][0];
    unsigned short* lA1 = &As[w * 32 + 16][0];
    unsigned short* lB0 = &Bs[w * 32][0];
    unsigned short* lB1 = &Bs[w * 32 + 16][0];

    const int n  = lane & 15;
    const int g8 = (lane >> 4) * 8;

    f32x4 acc[4][4];
    #pragma unroll
    for (int i = 0; i < 4; ++i)
        #pragma unroll
        for (int j = 0; j < 4; ++j) acc[i][j] = (f32x4){0.f, 0.f, 0.f, 0.f};

    for (int k0 = 0; k0 < K; k0 += 32) {
        load_lds16(ag0, lA0);
        load_lds16(ag1, lA1);
        load_lds16(bg0, lB0);
        load_lds16(bg1, lB1);
        ag0 += 32; ag1 += 32; bg0 += 32; bg1 += 32;
        __syncthreads();                       // drains vmcnt -> tiles visible

        short8 af[4], bf[4];
        #pragma unroll
        for (int t = 0; t < 4; ++t) {
            af[t] = *(const short8*)&As[wr + t * 16 + n][g8];
            bf[t] = *(const short8*)&Bs[wc + t * 16 + n][g8];
        }
        #pragma unroll
        for (int i = 0; i < 4; ++i)
            #pragma unroll
            for (int j = 0; j < 4; ++j)
                acc[i][j] = __builtin_amdgcn_mfma_f32_16x16x32_bf16(
                    af[i], bf[j], acc[i][j], 0, 0, 0);
        __syncthreads();                       // reads done before next overwrite
    }

    const bool second = (bn >= nsplit);
    const float* bp = second ? bias2 : bias1;
    const int boff = second ? nsplit : 0;
    const int crow0 = bm + wr + (lane >> 4) * 4;
    const int ccol0 = bn + wc + n;
    float bvals[4];
    #pragma unroll
    for (int j = 0; j < 4; ++j) bvals[j] = bp[ccol0 + j * 16 - boff];
    #pragma unroll
    for (int i = 0; i < 4; ++i)
        #pragma unroll
        for (int j = 0; j < 4; ++j) {
            const int col = ccol0 + j * 16;
            #pragma unroll
            for (int r = 0; r < 4; ++r) {
                const float v = acc[i][j][r] + bvals[j];
                const long long idx = (long long)(crow0 + i * 16 + r) * N + col;
                if (BF16OUT) ((unsigned short*)Cv)[idx] = f2b(v);
                else         ((float*)Cv)[idx] = v;
            }
        }
}

// ---------------------------------------------------------------------------
// EXPERIMENT ARM: gemm_pipe — depth-2 pipelined (3 LDS buffers, counted
// vmcnt, raw s_barrier). Used for K-proj and out-proj.
// Pipeline safety: stage(t+2) writes buf[(t+2)%3]; iter-t readers use
// buf[t%3]; laggards (iter t-1) use buf[(t-1)%3] == buf[(t+2)%3], so the
// stage is issued only AFTER the barrier (readers' ds_reads retired via
// lgkmcnt before their MFMAs -> before barrier arrival).
// vmcnt: at iter-t top a wave has stage(t)+stage(t+1) outstanding (8);
// vmcnt(4) retires the oldest 4 = stage(t) -> buf[t%3] complete.
// No-deadlock: vmcnt(N) is a no-op when outstanding<=N; all barriers are
// reached by all threads (nt and stage predicate are block-uniform).
// ---------------------------------------------------------------------------
template<bool BF16OUT>
__global__ __launch_bounds__(256)
void gemm_pipe(const unsigned short* __restrict__ A, const unsigned short* __restrict__ Bt,
               const float* __restrict__ bias1, const float* __restrict__ bias2, int nsplit,
               void* __restrict__ Cv, int N, int K, int lda, int group, long long gstride)
{
    __shared__ __align__(16) unsigned short As[3][128][32];   // 3 x 8 KB
    __shared__ __align__(16) unsigned short Bs[3][128][32];   // 3 x 8 KB

    const int tid  = threadIdx.x;
    const int w    = tid >> 6;
    const int lane = tid & 63;
    const int bm = blockIdx.y * 128;
    const int bn = blockIdx.x * 128;
    const int wr = (w >> 1) * 64;
    const int wc = (w & 1) * 64;

    const int srow   = w * 32 + (lane >> 2);
    const int schunk = (lane & 3) * 8;
    const int am0 = bm + srow;
    const int am1 = am0 + 16;
    const unsigned short* ag0 = A + (long long)(am0 / group) * gstride
                                  + (long long)(am0 % group) * lda + schunk;
    const unsigned short* ag1 = A + (long long)(am1 / group) * gstride
                                  + (long long)(am1 % group) * lda + schunk;
    const unsigned short* bg0 = Bt + (long long)(bn + srow) * K + schunk;
    const unsigned short* bg1 = bg0 + (long long)16 * K;

    const int n  = lane & 15;
    const int g8 = (lane >> 4) * 8;

    const int nt = K >> 5;                 // K-steps of 32

    // prologue: stage K-steps 0 and 1 into buffers 0 and 1
    load_lds16(ag0, &As[0][w * 32][0]);
    load_lds16(ag1, &As[0][w * 32 + 16][0]);
    load_lds16(bg0, &Bs[0][w * 32][0]);
    load_lds16(bg1, &Bs[0][w * 32 + 16][0]);
    load_lds16(ag0 + 32, &As[1][w * 32][0]);
    load_lds16(ag1 + 32, &As[1][w * 32 + 16][0]);
    load_lds16(bg0 + 32, &Bs[1][w * 32][0]);
    load_lds16(bg1 + 32, &Bs[1][w * 32 + 16][0]);

    f32x4 acc[4][4];
    #pragma unroll
    for (int i = 0; i < 4; ++i)
        #pragma unroll
        for (int j = 0; j < 4; ++j) acc[i][j] = (f32x4){0.f, 0.f, 0.f, 0.f};

    int cur = 0;                            // t % 3
    for (int t = 0; t < nt; ++t) {
        if (t == nt - 1) asm volatile("s_waitcnt vmcnt(0)" ::: "memory");
        else             asm volatile("s_waitcnt vmcnt(4)" ::: "memory");
        __builtin_amdgcn_s_barrier();

        // stage K-step t+2 into buf[(t+2)%3]
        if (t + 2 < nt) {
            const int b2 = cur + 2 >= 3 ? cur - 1 : cur + 2;
            const int ko = (t + 2) << 5;
            load_lds16(ag0 + ko, &As[b2][w * 32][0]);
            load_lds16(ag1 + ko, &As[b2][w * 32 + 16][0]);
            load_lds16(bg0 + ko, &Bs[b2][w * 32][0]);
            load_lds16(bg1 + ko, &Bs[b2][w * 32 + 16][0]);
        }

        short8 af[4], bf[4];
        #pragma unroll
        for (int tt = 0; tt < 4; ++tt) {
            af[tt] = *(const short8*)&As[cur][wr + tt * 16 + n][g8];
            bf[tt] = *(const short8*)&Bs[cur][wc + tt * 16 + n][g8];
        }
        #pragma unroll
        for (int i = 0; i < 4; ++i)
            #pragma unroll
            for (int j = 0; j < 4; ++j)
                acc[i][j] = __builtin_amdgcn_mfma_f32_16x16x32_bf16(
                    af[i], bf[j], acc[i][j], 0, 0, 0);

        cur = cur + 1 >= 3 ? 0 : cur + 1;
    }

    const bool second = (bn >= nsplit);
    const float* bp = second ? bias2 : bias1;
    const int boff = second ? nsplit : 0;
    const int crow0 = bm + wr + (lane >> 4) * 4;
    const int ccol0 = bn + wc + n;
    float bvals[4];
    #pragma unroll
    for (int j = 0; j < 4; ++j) bvals[j] = bp[ccol0 + j * 16 - boff];
    #pragma unroll
    for (int i = 0; i < 4; ++i)
        #pragma unroll
        for (int j = 0; j < 4; ++j) {
            const int col = ccol0 + j * 16;
            #pragma unroll
            for (int r = 0; r < 4; ++r) {
                const float v = acc[i][j][r] + bvals[j];
                const long long idx = (long long)(crow0 + i * 16 + r) * N + col;
                if (BF16OUT) ((unsigned short*)Cv)[idx] = f2b(v);
                else         ((float*)Cv)[idx] = v;
            }
        }
}

// ---------------------------------------------------------------------------
// MFMA attention: one block per (b,h), all 5 lags fused (Q, V^T staged once).
// (unchanged from the PASSING round-4 kernel)
// ---------------------------------------------------------------------------
__global__ __launch_bounds__(256)
void attn_mfma_kernel(const unsigned short* __restrict__ QV,
                      const unsigned short* __restrict__ Kp,
                      unsigned short* __restrict__ inter)
{
    __shared__ __align__(16) unsigned short PK[128 * 136];  // P region / K region (aliased)
    __shared__ __align__(16) unsigned short Vt[64 * 136];   // V transposed [d][j]

    const int bid = blockIdx.x;            // b*8 + h
    const int h = bid & 7;
    const int b = bid >> 3;
    const int tid = threadIdx.x;
    const int w = tid >> 6, lane = tid & 63;
    const int n = lane & 15, g = lane >> 4;
    const int g8 = g * 8;
    const int wr = w * 32;

    // ---- stage V transposed: thread t covers row j=t>>1, d-chunk (t&1)*32 ----
    {
        const int j = tid >> 1, d0 = (tid & 1) * 32;
        const unsigned short* vsrc = QV + ((long long)(b * SEQC + j)) * (2 * DIMC)
                                        + DIMC + h * DHC + d0;
        ushort8 vv[4];
        #pragma unroll
        for (int c = 0; c < 4; ++c) vv[c] = *(const ushort8*)(vsrc + c * 8);
        #pragma unroll
        for (int c = 0; c < 4; ++c)
            #pragma unroll
            for (int e = 0; e < 8; ++e)
                Vt[(d0 + c * 8 + e) * 136 + j] = vv[c][e];
    }

    // ---- Q fragments in regs for whole kernel: rows wr+rb*16+n, k=ks*32+g8 ----
    short8 qf[2][2];
    #pragma unroll
    for (int rb = 0; rb < 2; ++rb)
        #pragma unroll
        for (int ks = 0; ks < 2; ++ks)
            qf[rb][ks] = *(const short8*)(QV + ((long long)(b * SEQC + wr + rb * 16 + n)) * (2 * DIMC)
                                             + h * DHC + ks * 32 + g8);

    // ---- K load mapping: thread t covers row j=t>>1, chunk (t&1)*32 ----
    const int jrow = tid >> 1, jc = (tid & 1) * 32;
    const unsigned short* ksrc = Kp + ((long long)((b * LAGC) * SEQC + jrow)) * DIMC
                                    + h * DHC + jc;
    ushort8 kreg[4];
    #pragma unroll
    for (int c = 0; c < 4; ++c) kreg[c] = *(const ushort8*)(ksrc + c * 8);

    // causal block ranges for this wave (32-col aligned coverage)
    const int cbm0 = (2 * w + 0) | 1;      // S col-blocks for rb=0: cb <= cbm0
    const int cbm1 = (2 * w + 1) | 1;      // rb=1
    const int nk0 = (cbm0 + 1) >> 1;       // PV k-blocks (32 wide) for rb=0
    const int nk1 = (cbm1 + 1) >> 1;

    for (int l = 0; l < LAGC; ++l) {
        __syncthreads();                   // bar1: P/K region free (prev PV reads done)
        #pragma unroll
        for (int c = 0; c < 4; ++c)
            *(ushort8*)&PK[jrow * 72 + jc + c * 8] = kreg[c];   // K region, stride 72
        __syncthreads();                   // bar2: K (and, on l=0, Vt) visible

        // ---- S = Q K^T ----
        f32x4 accs[2][8];
        #pragma unroll
        for (int cb = 0; cb < 8; ++cb) {
            if (cb <= cbm1) {
                const short8 bf0 = *(const short8*)&PK[(cb * 16 + n) * 72 + g8];
                const short8 bf1 = *(const short8*)&PK[(cb * 16 + n) * 72 + 32 + g8];
                if (cb <= cbm0) {
                    accs[0][cb] = (f32x4){0.f, 0.f, 0.f, 0.f};
                    accs[0][cb] = __builtin_amdgcn_mfma_f32_16x16x32_bf16(qf[0][0], bf0, accs[0][cb], 0, 0, 0);
                    accs[0][cb] = __builtin_amdgcn_mfma_f32_16x16x32_bf16(qf[0][1], bf1, accs[0][cb], 0, 0, 0);
                }
                accs[1][cb] = (f32x4){0.f, 0.f, 0.f, 0.f};
                accs[1][cb] = __builtin_amdgcn_mfma_f32_16x16x32_bf16(qf[1][0], bf0, accs[1][cb], 0, 0, 0);
                accs[1][cb] = __builtin_amdgcn_mfma_f32_16x16x32_bf16(qf[1][1], bf1, accs[1][cb], 0, 0, 0);
            }
        }
        __syncthreads();                   // bar3: all waves done reading K region

        // ---- prefetch next lag's K into regs (hides under softmax+PV) ----
        if (l + 1 < LAGC) {
            const unsigned short* knext = ksrc + (long long)(l + 1) * SEQC * DIMC;
            #pragma unroll
            for (int c = 0; c < 4; ++c) kreg[c] = *(const ushort8*)(knext + c * 8);
        }

        // ---- no-max softmax + P(bf16) -> LDS (stride 136) ----
        float inv[2][4];
        #pragma unroll
        for (int rb = 0; rb < 2; ++rb) {
            const int cbm = rb ? cbm1 : cbm0;
            float ps[4] = {0.f, 0.f, 0.f, 0.f};
            #pragma unroll
            for (int cb = 0; cb < 8; ++cb) {
                if (cb <= cbm) {
                    const int j = cb * 16 + n;
                    #pragma unroll
                    for (int r = 0; r < 4; ++r) {
                        const int qr = wr + rb * 16 + 4 * g + r;
                        float p = __builtin_exp2f(accs[rb][cb][r] * 0.18033688f);
                        p = (j <= qr) ? p : 0.f;
                        ps[r] += p;
                        PK[qr * 136 + j] = f2b(p);
                    }
                }
            }
            #pragma unroll
            for (int r = 0; r < 4; ++r) {
                float s = ps[r];
                s += __shfl_xor(s, 1, 64);
                s += __shfl_xor(s, 2, 64);
                s += __shfl_xor(s, 4, 64);
                s += __shfl_xor(s, 8, 64);
                inv[rb][r] = 1.f / s;
            }
        }

        asm volatile("s_waitcnt lgkmcnt(0)" ::: "memory");   // P writes visible wave-wide

        // ---- O = P V ----
        f32x4 acco[2][4];
        #pragma unroll
        for (int rb = 0; rb < 2; ++rb)
            #pragma unroll
            for (int db = 0; db < 4; ++db) acco[rb][db] = (f32x4){0.f, 0.f, 0.f, 0.f};
        #pragma unroll
        for (int ks2 = 0; ks2 < 4; ++ks2) {
            if (ks2 < nk1) {
                short8 bv[4];
                #pragma unroll
                for (int db = 0; db < 4; ++db)
                    bv[db] = *(const short8*)&Vt[(db * 16 + n) * 136 + ks2 * 32 + g8];
                const short8 pa1 = *(const short8*)&PK[(wr + 16 + n) * 136 + ks2 * 32 + g8];
                if (ks2 < nk0) {
                    const short8 pa0 = *(const short8*)&PK[(wr + n) * 136 + ks2 * 32 + g8];
                    #pragma unroll
                    for (int db = 0; db < 4; ++db)
                        acco[0][db] = __builtin_amdgcn_mfma_f32_16x16x32_bf16(pa0, bv[db], acco[0][db], 0, 0, 0);
                }
                #pragma unroll
                for (int db = 0; db < 4; ++db)
                    acco[1][db] = __builtin_amdgcn_mfma_f32_16x16x32_bf16(pa1, bv[db], acco[1][db], 0, 0, 0);
            }
        }

        // ---- O store: inter[(b*S+q)*2560 + l*512 + h*64 + d], bf16 ----
        unsigned short* obase = inter + (long long)(b * SEQC) * (LAGC * DIMC)
                                      + l * DIMC + h * DHC;
        #pragma unroll
        for (int rb = 0; rb < 2; ++rb)
            #pragma unroll
            for (int db = 0; db < 4; ++db)
                #pragma unroll
                for (int r = 0; r < 4; ++r) {
                    const int qr = wr + rb * 16 + 4 * g + r;
                    obase[(long long)qr * (LAGC * DIMC) + db * 16 + n] =
                        f2b(acco[rb][db][r] * inv[rb][r]);
                }
    }
}

// ---------------------------------------------------------------------------
extern "C" void kernel_launch(void* const* d_in, const int* in_sizes, int n_in,
                              void* d_out, int out_size, void* d_ws, size_t ws_size,
                              hipStream_t stream)
{
    const float* input = (const float*)d_in[0];
    const float* Wq = (const float*)d_in[1];
    const float* bq = (const float*)d_in[2];
    const float* Wk = (const float*)d_in[3];
    const float* bk = (const float*)d_in[4];
    const float* Wv = (const float*)d_in[5];
    const float* bv = (const float*)d_in[6];
    const float* Wo = (const float*)d_in[7];
    const float* bo = (const float*)d_in[8];
    float* out = (float*)d_out;

    const long long MQ = (long long)BATCHC * SEQC;          // 8192
    const long long MK = (long long)BATCHC * LAGC * SEQC;   // 40960
    const int BIG = 1 << 30;

    // workspace layout (bf16 everywhere; ~147 MB total)
    unsigned short* in_bf = (unsigned short*)d_ws;          // 40960 x 512
    unsigned short* Wqvt  = in_bf + MK * DIMC;              // 1024 x 512 ([Wq|Wv]^T)
    unsigned short* Wkt   = Wqvt + (long long)2 * DIMC * DIMC;
    unsigned short* Wot   = Wkt + (long long)DIMC * DIMC;   // 512 x 2560
    unsigned short* QV    = Wot + (long long)DIMC * (LAGC * DIMC);  // 8192 x 1024
    unsigned short* Kb    = QV + MQ * (2 * DIMC);           // 40960 x 512
    unsigned short* inter = Kb + MK * DIMC;                 // 8192 x 2560

    // pre-passes: activation convert + all 4 weight transposes in one launch
    f32_to_bf16_kernel<<<2048, 256, 0, stream>>>(input, in_bf, MK * DIMC / 8);
    transpose4_bf16_kernel<<<dim3(LAGC * DIMC / 32, DIMC / 32, 4), 256, 0, stream>>>(
        Wq, Wv, Wk, Wo,
        Wqvt, Wqvt + (long long)DIMC * DIMC, Wkt, Wot);

    const long long bstride = (long long)LAGC * SEQC * DIMC;
    const unsigned short* last_bf = in_bf + (long long)(LAGC - 1) * SEQC * DIMC;

    // CONTROL: fused Q|V projection on the proven base structure
    gemm_base<true><<<dim3(2 * DIMC / 128, MQ / 128), 256, 0, stream>>>(
        last_bf, Wqvt, bq, bv, DIMC, QV, 2 * DIMC, DIMC, DIMC, SEQC, bstride);
    // EXPERIMENT: K projection on the pipelined structure
    gemm_pipe<true><<<dim3(DIMC / 128, MK / 128), 256, 0, stream>>>(
        in_bf, Wkt, bk, bk, BIG, Kb, DIMC, DIMC, DIMC, BIG, 0);

    // attention: one block per (b,h), 5 lags fused
    attn_mfma_kernel<<<dim3(BATCHC * NHEADS), 256, 0, stream>>>(QV, Kb, inter);

    // EXPERIMENT: out-proj on the pipelined structure
    gemm_pipe<false><<<dim3(DIMC / 128, MQ / 128), 256, 0, stream>>>(
        inter, Wot, bo, bo, BIG, out, DIMC, LAGC * DIMC, LAGC * DIMC, BIG, 0);
}